// Round 9
// baseline (189.089 us; speedup 1.0000x reference)
//
#include <hip/hip_runtime.h>
#include <hip/hip_fp16.h>
#include <array>

// ============================================================================
// R9 = MEASUREMENT ROUND. Kernels are BIT-IDENTICAL to R8. topk7 is launched
// 3x (idempotent: rows is a pure function of anat) so that
//   T9 - T8 = 2 * topk_dur
// pins the per-kernel split that the top-5 profile (all harness fill) hides.
// ============================================================================

// Problem constants (reference: H=64, M=N=128, k=9, w=3)
constexpr int HZ   = 64;
constexpr int NN   = 128;
constexpr int P    = HZ * NN * NN;    // 1,048,576 voxels
constexpr int KSEL = 9;
constexpr int NCOL = 27;              // 3x3x3 window
constexpr int STD  = 8;               // fp16 row stride in dwords (32 B)

typedef _Float16 f16x2 __attribute__((ext_vector_type(2)));

constexpr int TY = 10;   // 8 core + 2 halo
constexpr int TX = 34;   // 32 core + 2 halo

// ---------------------------------------------------------------------------
// Batcher merge-exchange network for n=27 + backward dead-CE pruning.
// ---------------------------------------------------------------------------
constexpr int compute_nce(int n) {
  int t = 0; while ((1 << t) < n) ++t;
  int cnt = 0;
  for (int p = 1 << (t - 1); p > 0; p >>= 1) {
    int q = 1 << (t - 1), r = 0, d = p;
    while (true) {
      for (int i = 0; i < n - d; ++i)
        if ((i & p) == r) ++cnt;
      if (q == p) break;
      d = q - p; r = p; q >>= 1;
    }
  }
  return cnt;
}
constexpr int NCE_FULL = compute_nce(NCOL);   // 155

struct CEPair { unsigned char a, b; };
constexpr std::array<CEPair, NCE_FULL> make_net() {
  std::array<CEPair, NCE_FULL> net{};
  int t = 0; while ((1 << t) < NCOL) ++t;
  int k = 0;
  for (int p = 1 << (t - 1); p > 0; p >>= 1) {
    int q = 1 << (t - 1), r = 0, d = p;
    while (true) {
      for (int i = 0; i < NCOL - d; ++i)
        if ((i & p) == r) {
          net[k].a = (unsigned char)i;
          net[k].b = (unsigned char)(i + d);
          ++k;
        }
      if (q == p) break;
      d = q - p; r = p; q >>= 1;
    }
  }
  return net;
}
constexpr auto FULLNET = make_net();

constexpr int count_pruned() {
  bool needed[NCOL] = {};
  for (int i = 0; i < KSEL; ++i) needed[i] = true;
  int cnt = 0;
  for (int e = NCE_FULL - 1; e >= 0; --e) {
    const int a = FULLNET[e].a, b = FULLNET[e].b;
    if (needed[a] || needed[b]) { needed[a] = true; needed[b] = true; ++cnt; }
  }
  return cnt;
}
constexpr int NCE = count_pruned();

constexpr std::array<CEPair, NCE> make_pruned() {
  bool needed[NCOL] = {};
  for (int i = 0; i < KSEL; ++i) needed[i] = true;
  std::array<bool, NCE_FULL> keep{};
  for (int e = NCE_FULL - 1; e >= 0; --e) {
    const int a = FULLNET[e].a, b = FULLNET[e].b;
    if (needed[a] || needed[b]) { keep[e] = true; needed[a] = true; needed[b] = true; }
  }
  std::array<CEPair, NCE> out{};
  int k = 0;
  for (int e = 0; e < NCE_FULL; ++e) if (keep[e]) out[k++] = FULLNET[e];
  return out;
}
constexpr auto NET = make_pruned();

// ---------------------------------------------------------------------------
// Pass 1 (identical to R8's topk7)
// ---------------------------------------------------------------------------
__global__ __launch_bounds__(256) void topk7(
    const float* __restrict__ anat,
    unsigned* __restrict__ rows) {
  __shared__ float in_t[3 * TY * TX];
  __shared__ unsigned lrow[256 * STD];
  const int tid = threadIdx.x;

  const int blk = blockIdx.x;
  const int swz = ((blk & 7) << 9) | (blk >> 3);
  const int z    = swz >> 6;
  const int rest = swz & 63;
  const int y0   = ((rest >> 2) & 15) << 3;
  const int x0   = (rest & 3) << 5;
  const int xl   = tid & 31;
  const int yl   = tid >> 5;

  #pragma unroll
  for (int s = 0; s < 4; ++s) {
    const unsigned q = (unsigned)(s * 256 + tid);
    if (q < (unsigned)(3 * TY * TX)) {
      const unsigned p = q / TX;
      const unsigned r = q - p * TX;
      const unsigned pz = p / TY;
      const int zi = (int)pz, yi = (int)(p - TY * pz);
      const int zz = (z + zi - 1) & (HZ - 1);
      const int yy = (y0 + yi - 1) & (NN - 1);
      const int xg = (x0 - 1 + (int)r) & (NN - 1);
      in_t[q] = anat[(zz << 14) | (yy << 7) | xg];
    }
  }
  __syncthreads();

  const int base = (yl * TX) + xl;
  const float center = in_t[base + 1 * (TY * TX) + 1 * TX + 1];

  unsigned long long key[NCOL];
  #pragma unroll
  for (int c = 0; c < NCOL; ++c) {
    const int czi = c / 9, cyi = (c / 3) % 3, cxi = c % 3;
    const float v = in_t[base + czi * (TY * TX) + cyi * TX + cxi];
    const unsigned vb = __float_as_uint(v);
    const unsigned db = __float_as_uint(v - center) & 0x7fffffffu;
    const unsigned hi32 = (db << 1) | ((unsigned)c >> 4);
    const unsigned lo32 = ((unsigned)c << 28) | (vb >> 4);
    key[c] = ((unsigned long long)hi32 << 32) | lo32;
  }

  #pragma unroll
  for (int e = 0; e < NCE; ++e) {
    const int a = NET[e].a, b = NET[e].b;
    const unsigned long long xk = key[a], yk = key[b];
    const bool sw = xk > yk;
    key[a] = sw ? yk : xk;
    key[b] = sw ? xk : yk;
  }

  unsigned d[5] = {0, 0, 0, 0, 0};
  unsigned lo = 0, hi = 0;
  #pragma unroll
  for (int s = 0; s < KSEL; ++s) {
    const unsigned c  = (unsigned)(key[s] >> 28) & 31u;
    const unsigned vb = ((unsigned)key[s] & 0x0fffffffu) << 4;
    const ushort hb = __half_as_ushort(__float2half(__uint_as_float(vb)));
    d[s >> 1] |= (unsigned)hb << ((s & 1) * 16);
    if (s < 6) lo |= c << (5 * s);
    else       hi |= c << (5 * (s - 6));
  }

  unsigned* myrow = &lrow[tid * STD];
  ((uint4*)myrow)[0] = make_uint4(d[0], d[1], d[2], d[3]);
  ((uint4*)myrow)[1] = make_uint4(d[4], lo, hi, 0u);

  __syncthreads();

  uint4* rows4 = (uint4*)rows;
  const uint4* l4 = (const uint4*)lrow;
  #pragma unroll
  for (int s = 0; s < 2; ++s) {
    const unsigned q   = (unsigned)(s * 256 + tid);
    const unsigned run = q >> 6;
    const unsigned off = q & 63u;
    const unsigned vb  = (unsigned)((z << 14) | ((y0 + (int)run) << 7) | x0);
    rows4[(size_t)vb * 2 + off] = l4[run * 64 + off];
  }
}

// ---------------------------------------------------------------------------
// Pass 2 (identical to R8's weights7)
// ---------------------------------------------------------------------------
constexpr int TROWS = 3 * TY * TX;   // 1020

__global__ __launch_bounds__(256) void weights7(
    const unsigned* __restrict__ rows,
    const float* __restrict__ ksig,
    float* __restrict__ out) {
  __shared__ unsigned tile[TROWS * STD];
  const int tid = threadIdx.x;

  const int blk = blockIdx.x;
  const int swz = ((blk & 7) << 9) | (blk >> 3);
  const int z    = swz >> 6;
  const int rest = swz & 63;
  const int y0   = ((rest >> 2) & 15) << 3;
  const int x0   = (rest & 3) << 5;
  const int xl   = tid & 31;
  const int yl   = tid >> 5;

  const uint4* rows4 = (const uint4*)rows;
  uint4* t4 = (uint4*)tile;
  #pragma unroll
  for (int s = 0; s < 8; ++s) {
    const unsigned q = (unsigned)(s * 256 + tid);
    if (q < 2040u) {
      const unsigned p   = q / 68u;
      const unsigned rem = q - p * 68u;
      const unsigned r   = rem >> 1;
      const unsigned c   = rem & 1u;
      const unsigned pz  = p / 10u;
      const int zi = (int)pz, yi = (int)(p - 10u * pz);
      const int zz = (z + zi - 1) & (HZ - 1);
      const int yy = (y0 + yi - 1) & (NN - 1);
      const int xg = (x0 - 1 + (int)r) & (NN - 1);
      t4[q] = rows4[(size_t)((zz << 14) | (yy << 7) | xg) * 2 + c];
    }
  }
  __syncthreads();

  const int rho_own = (TY + (yl + 1)) * TX + (xl + 1);
  const uint4 u0 = t4[rho_own * 2], u1 = t4[rho_own * 2 + 1];
  f16x2 wh[5];
  wh[0] = __builtin_bit_cast(f16x2, u0.x);
  wh[1] = __builtin_bit_cast(f16x2, u0.y);
  wh[2] = __builtin_bit_cast(f16x2, u0.z);
  wh[3] = __builtin_bit_cast(f16x2, u0.w);
  wh[4] = __builtin_bit_cast(f16x2, u1.x);
  const unsigned lo = u1.y;
  const unsigned hi = u1.z;

  float ws[KSEL];
  #pragma unroll
  for (int l = 0; l < KSEL; ++l) ws[l] = (float)wh[l >> 1][l & 1];
  float mean = 0.f;
  #pragma unroll
  for (int l = 0; l < KSEL; ++l) mean += ws[l];
  mean *= (1.0f / 9.0f);
  float var = 0.f;
  #pragma unroll
  for (int l = 0; l < KSEL; ++l) { const float t = ws[l] - mean; var += t * t; }
  var *= (1.0f / 8.0f);
  const float sigma = sqrtf(var);

  const float ks = ksig[0];
  const float inv = (sigma == 0.f) ? 0.f : 1.0f / (2.0f * ks * ks * sigma * sigma);

  const _Float16 epsh = (_Float16)1e-6f;
  const f16x2 eps2 = {epsh, epsh};

  float logit[KSEL];
  #pragma unroll
  for (int j = 0; j < KSEL; ++j) {
    const unsigned c = (j < 6) ? ((lo >> (5 * j)) & 31u)
                               : ((hi >> (5 * (j - 6))) & 31u);
    const unsigned czi = (c * 57u) >> 9;
    const unsigned rem = c - 9u * czi;
    const unsigned cyi = (rem * 11u) >> 5;
    const unsigned cxi = rem - 3u * cyi;
    const int rho = (int)czi * (TY * TX) + (yl + (int)cyi) * TX + (xl + (int)cxi);
    const uint4 n0 = t4[rho * 2], n1 = t4[rho * 2 + 1];
    float s = 0.f;
    const f16x2 nh0 = __builtin_bit_cast(f16x2, n0.x);
    const f16x2 nh1 = __builtin_bit_cast(f16x2, n0.y);
    const f16x2 nh2 = __builtin_bit_cast(f16x2, n0.z);
    const f16x2 nh3 = __builtin_bit_cast(f16x2, n0.w);
    const f16x2 nh4 = __builtin_bit_cast(f16x2, n1.x);
    f16x2 dd;
    dd = (wh[0] - nh0) + eps2; s = __builtin_amdgcn_fdot2(dd, dd, s, false);
    dd = (wh[1] - nh1) + eps2; s = __builtin_amdgcn_fdot2(dd, dd, s, false);
    dd = (wh[2] - nh2) + eps2; s = __builtin_amdgcn_fdot2(dd, dd, s, false);
    dd = (wh[3] - nh3) + eps2; s = __builtin_amdgcn_fdot2(dd, dd, s, false);
    dd = (wh[4] - nh4) + eps2; s = __builtin_amdgcn_fdot2(dd, dd, s, false);
    logit[j] = -s * inv;
  }

  float mx = logit[0];
  #pragma unroll
  for (int j = 1; j < KSEL; ++j) mx = fmaxf(mx, logit[j]);
  float sum = 0.f;
  float e[KSEL];
  #pragma unroll
  for (int j = 0; j < KSEL; ++j) { e[j] = __expf(logit[j] - mx); sum += e[j]; }
  const float rs = 1.0f / sum;

  __syncthreads();
  float* tf = (float*)tile;
  #pragma unroll
  for (int j = 0; j < KSEL; ++j) tf[tid * KSEL + j] = e[j] * rs;
  __syncthreads();

  const float4* tf4 = (const float4*)tile;
  #pragma unroll
  for (int s = 0; s < 3; ++s) {
    const unsigned q = (unsigned)(s * 256 + tid);
    if (q < 576u) {
      const unsigned row = q / 72u;
      const unsigned f   = q - row * 72u;
      const unsigned vb  = (unsigned)((z << 14) | ((y0 + (int)row) << 7) | x0);
      ((float4*)out)[(size_t)(vb >> 2) * 9 + f] = tf4[row * 72 + f];
    }
  }
}

// ---------------------------------------------------------------------------
// MEASUREMENT: topk7 launched 3x (idempotent), weights7 1x.
// T9 - T8 = 2 * topk_dur.
// ---------------------------------------------------------------------------
extern "C" void kernel_launch(void* const* d_in, const int* in_sizes, int n_in,
                              void* d_out, int out_size, void* d_ws, size_t ws_size,
                              hipStream_t stream) {
  const float* anat = (const float*)d_in[0];
  const float* ksig = (const float*)d_in[1];
  unsigned* rows = (unsigned*)d_ws;

  const int blocks = P / 256;
  topk7<<<blocks, 256, 0, stream>>>(anat, rows);
  topk7<<<blocks, 256, 0, stream>>>(anat, rows);
  topk7<<<blocks, 256, 0, stream>>>(anat, rows);
  weights7<<<blocks, 256, 0, stream>>>(rows, ksig, (float*)d_out);
}

// Round 10
// 122.621 us; speedup vs baseline: 1.5421x; 1.5421x over previous
//
#include <hip/hip_runtime.h>
#include <hip/hip_fp16.h>
#include <array>

// Problem constants (reference: H=64, M=N=128, k=9, w=3)
constexpr int HZ   = 64;
constexpr int NN   = 128;
constexpr int P    = HZ * NN * NN;    // 1,048,576 voxels
constexpr int KSEL = 9;
constexpr int NCOL = 27;              // 3x3x3 window
constexpr int STD  = 8;               // fp16 row stride in dwords (32 B)

typedef _Float16 f16x2 __attribute__((ext_vector_type(2)));

constexpr int TY = 10;   // 8 core + 2 halo
constexpr int TX = 34;   // 32 core + 2 halo

// ---------------------------------------------------------------------------
// Batcher merge-exchange network for n=27 + backward dead-CE pruning.
// ---------------------------------------------------------------------------
constexpr int compute_nce(int n) {
  int t = 0; while ((1 << t) < n) ++t;
  int cnt = 0;
  for (int p = 1 << (t - 1); p > 0; p >>= 1) {
    int q = 1 << (t - 1), r = 0, d = p;
    while (true) {
      for (int i = 0; i < n - d; ++i)
        if ((i & p) == r) ++cnt;
      if (q == p) break;
      d = q - p; r = p; q >>= 1;
    }
  }
  return cnt;
}
constexpr int NCE_FULL = compute_nce(NCOL);   // 155

struct CEPair { unsigned char a, b; };
constexpr std::array<CEPair, NCE_FULL> make_net() {
  std::array<CEPair, NCE_FULL> net{};
  int t = 0; while ((1 << t) < NCOL) ++t;
  int k = 0;
  for (int p = 1 << (t - 1); p > 0; p >>= 1) {
    int q = 1 << (t - 1), r = 0, d = p;
    while (true) {
      for (int i = 0; i < NCOL - d; ++i)
        if ((i & p) == r) {
          net[k].a = (unsigned char)i;
          net[k].b = (unsigned char)(i + d);
          ++k;
        }
      if (q == p) break;
      d = q - p; r = p; q >>= 1;
    }
  }
  return net;
}
constexpr auto FULLNET = make_net();

constexpr int count_pruned() {
  bool needed[NCOL] = {};
  for (int i = 0; i < KSEL; ++i) needed[i] = true;
  int cnt = 0;
  for (int e = NCE_FULL - 1; e >= 0; --e) {
    const int a = FULLNET[e].a, b = FULLNET[e].b;
    if (needed[a] || needed[b]) { needed[a] = true; needed[b] = true; ++cnt; }
  }
  return cnt;
}
constexpr int NCE = count_pruned();

constexpr std::array<CEPair, NCE> make_pruned() {
  bool needed[NCOL] = {};
  for (int i = 0; i < KSEL; ++i) needed[i] = true;
  std::array<bool, NCE_FULL> keep{};
  for (int e = NCE_FULL - 1; e >= 0; --e) {
    const int a = FULLNET[e].a, b = FULLNET[e].b;
    if (needed[a] || needed[b]) { keep[e] = true; needed[a] = true; needed[b] = true; }
  }
  std::array<CEPair, NCE> out{};
  int k = 0;
  for (int e = 0; e < NCE_FULL; ++e) if (keep[e]) out[k++] = FULLNET[e];
  return out;
}
constexpr auto NET = make_pruned();

// ---------------------------------------------------------------------------
// Pass 1 (R10): key = db<<32 | col<<27 | vbits>>5 (63 bits, sign bit 0).
// For non-negative, non-NaN doubles, IEEE order == unsigned order, so each
// compare-exchange is v_min_f64 + v_max_f64 (2 instr vs 5 for u64 cmp+cndmask).
// NaN patterns would need |v-c| = inf/nan (impossible). Denormal-double keys
// occur only for dist==0 (self col); GCN f64 honors denormals (no flush).
// Order = (db, col) exactly -> exact NumPy stable order.
// ---------------------------------------------------------------------------
__global__ __launch_bounds__(256) void topk8(
    const float* __restrict__ anat,
    unsigned* __restrict__ rows) {
  __shared__ float in_t[3 * TY * TX];   // 4.08 KB input halo
  __shared__ unsigned lrow[256 * STD];  // 8 KB output staging
  const int tid = threadIdx.x;

  const int blk = blockIdx.x;
  const int swz = ((blk & 7) << 9) | (blk >> 3);   // 8 XCDs x 512-slab
  const int z    = swz >> 6;
  const int rest = swz & 63;
  const int y0   = ((rest >> 2) & 15) << 3;
  const int x0   = (rest & 3) << 5;
  const int xl   = tid & 31;
  const int yl   = tid >> 5;

  #pragma unroll
  for (int s = 0; s < 4; ++s) {
    const unsigned q = (unsigned)(s * 256 + tid);
    if (q < (unsigned)(3 * TY * TX)) {
      const unsigned p = q / TX;
      const unsigned r = q - p * TX;
      const unsigned pz = p / TY;
      const int zi = (int)pz, yi = (int)(p - TY * pz);
      const int zz = (z + zi - 1) & (HZ - 1);
      const int yy = (y0 + yi - 1) & (NN - 1);
      const int xg = (x0 - 1 + (int)r) & (NN - 1);
      in_t[q] = anat[(zz << 14) | (yy << 7) | xg];
    }
  }
  __syncthreads();

  const int base = (yl * TX) + xl;
  const float center = in_t[base + 1 * (TY * TX) + 1 * TX + 1];

  unsigned long long key[NCOL];
  #pragma unroll
  for (int c = 0; c < NCOL; ++c) {
    const int czi = c / 9, cyi = (c / 3) % 3, cxi = c % 3;
    const float v = in_t[base + czi * (TY * TX) + cyi * TX + cxi];
    const unsigned vb = __float_as_uint(v);
    const unsigned db = __float_as_uint(v - center) & 0x7fffffffu;
    const unsigned lo32 = ((unsigned)c << 27) | (vb >> 5);
    key[c] = ((unsigned long long)db << 32) | lo32;
  }

  // Pruned sorting network; CE = f64 min/max pair.
  #pragma unroll
  for (int e = 0; e < NCE; ++e) {
    const int a = NET[e].a, b = NET[e].b;
    const double ka = __builtin_bit_cast(double, key[a]);
    const double kb = __builtin_bit_cast(double, key[b]);
    key[a] = __builtin_bit_cast(unsigned long long, fmin(ka, kb));
    key[b] = __builtin_bit_cast(unsigned long long, fmax(ka, kb));
  }

  // Epilogue: col at [31:27] of low dword, value top-27 bits at [26:0].
  unsigned d[5] = {0, 0, 0, 0, 0};
  unsigned lo = 0, hi = 0;
  #pragma unroll
  for (int s = 0; s < KSEL; ++s) {
    const unsigned kl = (unsigned)key[s];
    const unsigned c  = (kl >> 27) & 31u;
    const unsigned vb = (kl & 0x07ffffffu) << 5;
    const ushort hb = __half_as_ushort(__float2half(__uint_as_float(vb)));
    d[s >> 1] |= (unsigned)hb << ((s & 1) * 16);
    if (s < 6) lo |= c << (5 * s);
    else       hi |= c << (5 * (s - 6));
  }

  unsigned* myrow = &lrow[tid * STD];
  ((uint4*)myrow)[0] = make_uint4(d[0], d[1], d[2], d[3]);
  ((uint4*)myrow)[1] = make_uint4(d[4], lo, hi, 0u);

  __syncthreads();

  uint4* rows4 = (uint4*)rows;
  const uint4* l4 = (const uint4*)lrow;
  #pragma unroll
  for (int s = 0; s < 2; ++s) {
    const unsigned q   = (unsigned)(s * 256 + tid);
    const unsigned run = q >> 6;
    const unsigned off = q & 63u;
    const unsigned vb  = (unsigned)((z << 14) | ((y0 + (int)run) << 7) | x0);
    rows4[(size_t)vb * 2 + off] = l4[run * 64 + off];
  }
}

// ---------------------------------------------------------------------------
// Pass 2 (R10): same staging/tiling as R8; all 9 neighbor addresses decoded
// first and all 18 ds_read_b128 batched into registers BEFORE the math
// (lgkmcnt pipelining instead of per-neighbor load->use serialization).
// ---------------------------------------------------------------------------
constexpr int TROWS = 3 * TY * TX;   // 1020

__global__ __launch_bounds__(256) void weights8(
    const unsigned* __restrict__ rows,
    const float* __restrict__ ksig,
    float* __restrict__ out) {
  __shared__ unsigned tile[TROWS * STD];   // 32640 B; reused for out staging
  const int tid = threadIdx.x;

  const int blk = blockIdx.x;
  const int swz = ((blk & 7) << 9) | (blk >> 3);
  const int z    = swz >> 6;
  const int rest = swz & 63;
  const int y0   = ((rest >> 2) & 15) << 3;
  const int x0   = (rest & 3) << 5;
  const int xl   = tid & 31;
  const int yl   = tid >> 5;

  const uint4* rows4 = (const uint4*)rows;
  uint4* t4 = (uint4*)tile;
  #pragma unroll
  for (int s = 0; s < 8; ++s) {
    const unsigned q = (unsigned)(s * 256 + tid);
    if (q < 2040u) {
      const unsigned p   = q / 68u;
      const unsigned rem = q - p * 68u;
      const unsigned r   = rem >> 1;
      const unsigned c   = rem & 1u;
      const unsigned pz  = p / 10u;
      const int zi = (int)pz, yi = (int)(p - 10u * pz);
      const int zz = (z + zi - 1) & (HZ - 1);
      const int yy = (y0 + yi - 1) & (NN - 1);
      const int xg = (x0 - 1 + (int)r) & (NN - 1);
      t4[q] = rows4[(size_t)((zz << 14) | (yy << 7) | xg) * 2 + c];
    }
  }
  __syncthreads();

  // Own row.
  const int rho_own = (TY + (yl + 1)) * TX + (xl + 1);
  const uint4 u0 = t4[rho_own * 2], u1 = t4[rho_own * 2 + 1];
  f16x2 wh[5];
  wh[0] = __builtin_bit_cast(f16x2, u0.x);
  wh[1] = __builtin_bit_cast(f16x2, u0.y);
  wh[2] = __builtin_bit_cast(f16x2, u0.z);
  wh[3] = __builtin_bit_cast(f16x2, u0.w);
  wh[4] = __builtin_bit_cast(f16x2, u1.x);
  const unsigned lo = u1.y;
  const unsigned hi = u1.z;

  // Decode all 9 neighbor tile addresses, then batch-issue all 18 reads.
  int rho[KSEL];
  #pragma unroll
  for (int j = 0; j < KSEL; ++j) {
    const unsigned c = (j < 6) ? ((lo >> (5 * j)) & 31u)
                               : ((hi >> (5 * (j - 6))) & 31u);
    const unsigned czi = (c * 57u) >> 9;
    const unsigned rem = c - 9u * czi;
    const unsigned cyi = (rem * 11u) >> 5;
    const unsigned cxi = rem - 3u * cyi;
    rho[j] = (int)czi * (TY * TX) + (yl + (int)cyi) * TX + (xl + (int)cxi);
  }
  uint4 nbuf[KSEL][2];
  #pragma unroll
  for (int j = 0; j < KSEL; ++j) {
    nbuf[j][0] = t4[rho[j] * 2];
    nbuf[j][1] = t4[rho[j] * 2 + 1];
  }

  // sigma with ddof=1 (two-pass, matches jnp.std).
  float ws[KSEL];
  #pragma unroll
  for (int l = 0; l < KSEL; ++l) ws[l] = (float)wh[l >> 1][l & 1];
  float mean = 0.f;
  #pragma unroll
  for (int l = 0; l < KSEL; ++l) mean += ws[l];
  mean *= (1.0f / 9.0f);
  float var = 0.f;
  #pragma unroll
  for (int l = 0; l < KSEL; ++l) { const float t = ws[l] - mean; var += t * t; }
  var *= (1.0f / 8.0f);
  const float sigma = sqrtf(var);

  const float ks = ksig[0];
  const float inv = (sigma == 0.f) ? 0.f : 1.0f / (2.0f * ks * ks * sigma * sigma);

  const _Float16 epsh = (_Float16)1e-6f;
  const f16x2 eps2 = {epsh, epsh};

  float logit[KSEL];
  #pragma unroll
  for (int j = 0; j < KSEL; ++j) {
    const f16x2 nh0 = __builtin_bit_cast(f16x2, nbuf[j][0].x);
    const f16x2 nh1 = __builtin_bit_cast(f16x2, nbuf[j][0].y);
    const f16x2 nh2 = __builtin_bit_cast(f16x2, nbuf[j][0].z);
    const f16x2 nh3 = __builtin_bit_cast(f16x2, nbuf[j][0].w);
    const f16x2 nh4 = __builtin_bit_cast(f16x2, nbuf[j][1].x);
    float s = 0.f;
    f16x2 dd;
    dd = (wh[0] - nh0) + eps2; s = __builtin_amdgcn_fdot2(dd, dd, s, false);
    dd = (wh[1] - nh1) + eps2; s = __builtin_amdgcn_fdot2(dd, dd, s, false);
    dd = (wh[2] - nh2) + eps2; s = __builtin_amdgcn_fdot2(dd, dd, s, false);
    dd = (wh[3] - nh3) + eps2; s = __builtin_amdgcn_fdot2(dd, dd, s, false);
    dd = (wh[4] - nh4) + eps2; s = __builtin_amdgcn_fdot2(dd, dd, s, false);
    logit[j] = -s * inv;
  }

  // softmax over the 9 logits
  float mx = logit[0];
  #pragma unroll
  for (int j = 1; j < KSEL; ++j) mx = fmaxf(mx, logit[j]);
  float sum = 0.f;
  float e[KSEL];
  #pragma unroll
  for (int j = 0; j < KSEL; ++j) { e[j] = __expf(logit[j] - mx); sum += e[j]; }
  const float rs = 1.0f / sum;

  // Output staging through LDS -> coalesced float4 stores.
  __syncthreads();
  float* tf = (float*)tile;
  #pragma unroll
  for (int j = 0; j < KSEL; ++j) tf[tid * KSEL + j] = e[j] * rs;
  __syncthreads();

  const float4* tf4 = (const float4*)tile;
  #pragma unroll
  for (int s = 0; s < 3; ++s) {
    const unsigned q = (unsigned)(s * 256 + tid);
    if (q < 576u) {
      const unsigned row = q / 72u;
      const unsigned f   = q - row * 72u;
      const unsigned vb  = (unsigned)((z << 14) | ((y0 + (int)row) << 7) | x0);
      ((float4*)out)[(size_t)(vb >> 2) * 9 + f] = tf4[row * 72 + f];
    }
  }
}

// ---------------------------------------------------------------------------
// d_in: [0] input (P floats), [1] ksigma (1 float), [2] k (int), [3] w (int)
// d_ws: fp16 row array, P * 8 dwords = 32 MB
// ---------------------------------------------------------------------------
extern "C" void kernel_launch(void* const* d_in, const int* in_sizes, int n_in,
                              void* d_out, int out_size, void* d_ws, size_t ws_size,
                              hipStream_t stream) {
  const float* anat = (const float*)d_in[0];
  const float* ksig = (const float*)d_in[1];
  unsigned* rows = (unsigned*)d_ws;

  const int blocks = P / 256;
  topk8<<<blocks, 256, 0, stream>>>(anat, rows);
  weights8<<<blocks, 256, 0, stream>>>(rows, ksig, (float*)d_out);
}